// Round 1
// baseline (1844.818 us; speedup 1.0000x reference)
//
#include <hip/hip_runtime.h>
#include <hip/hip_bf16.h>

#define NTOK 8192
#define CD 768
#define HD 3072
#define NE 4
#define MAX_TILES 132          // sum_e ceil(n_e/64) <= 128 + 3, +1 slack
#define GCAP (MAX_TILES * 64)  // 8448 grouped (padded) rows

// ---------------- ws layout (byte offsets) ----------------
// [0       , 32768 ) expert_idx  int[8192]
// [32768   , 32784 ) counts      int[4]
// [32784   , 32800 ) fill        int[4]
// [32800   , 33328 ) tile_expert int[132]
// [33344   , 33360 ) sum_probs   float[4]
// [33360   , 33364 ) z_sum       float
// [33364   , 33368 ) h_sum       float
// [33792   , 67584 ) token_list  int[8448]
// [131072  , ...   ) hbuf        bf16[8448*3072]  (~51.9 MB)

__global__ void k_init(int* counts, int* fill, int* tilee,
                       float* sprob, float* zsum, float* hsum, int* tlist) {
    int t = threadIdx.x;
    if (t < NE) { counts[t] = 0; fill[t] = 0; sprob[t] = 0.f; }
    if (t == NE) { *zsum = 0.f; *hsum = 0.f; }
    for (int i = t; i < MAX_TILES; i += 256) tilee[i] = -1;
    for (int i = t; i < GCAP; i += 256) tlist[i] = -1;
}

// one wave per token: fp32 logits, softmax stats, argmax
__global__ __launch_bounds__(256) void k_router(
        const float* __restrict__ x, const float* __restrict__ wr,
        int* __restrict__ eidx, int* __restrict__ counts,
        float* __restrict__ sprob, float* __restrict__ zsum, float* __restrict__ hsum) {
    int lane = threadIdx.x & 63;
    int t = blockIdx.x * 4 + (threadIdx.x >> 6);
    const float* xr = x + (size_t)t * CD;
    float a0 = 0.f, a1 = 0.f, a2 = 0.f, a3 = 0.f;
    #pragma unroll
    for (int j = 0; j < CD; j += 64) {
        float xv = xr[j + lane];
        a0 = fmaf(xv, wr[0 * CD + j + lane], a0);
        a1 = fmaf(xv, wr[1 * CD + j + lane], a1);
        a2 = fmaf(xv, wr[2 * CD + j + lane], a2);
        a3 = fmaf(xv, wr[3 * CD + j + lane], a3);
    }
    #pragma unroll
    for (int off = 32; off > 0; off >>= 1) {
        a0 += __shfl_xor(a0, off);
        a1 += __shfl_xor(a1, off);
        a2 += __shfl_xor(a2, off);
        a3 += __shfl_xor(a3, off);
    }
    if (lane == 0) {
        float l[NE] = {a0, a1, a2, a3};
        int best = 0; float m = l[0];
        #pragma unroll
        for (int e = 1; e < NE; ++e) if (l[e] > m) { m = l[e]; best = e; }
        float p[NE], s = 0.f;
        #pragma unroll
        for (int e = 0; e < NE; ++e) { p[e] = expf(l[e] - m); s += p[e]; }
        float inv = 1.f / s;
        float ent = 0.f;
        #pragma unroll
        for (int e = 0; e < NE; ++e) {
            p[e] *= inv;
            ent -= p[e] * logf(p[e] + 1e-9f);
            atomicAdd(&sprob[e], p[e]);
        }
        float lse = m + logf(s);
        atomicAdd(zsum, lse * lse);
        atomicAdd(hsum, ent);
        atomicAdd(&counts[best], 1);
        eidx[t] = best;
    }
}

// single-thread scan: per-expert padded bases + tile->expert map
__global__ void k_scan(const int* counts, int* fill, int* tilee) {
    int base = 0, nt = 0;
    for (int e = 0; e < NE; ++e) {
        fill[e] = base;
        int tiles = (counts[e] + 63) >> 6;
        for (int i = 0; i < tiles; ++i) tilee[nt++] = e;
        base += tiles << 6;
    }
}

__global__ void k_scatter(const int* __restrict__ eidx, int* __restrict__ fill,
                          int* __restrict__ tlist) {
    int t = blockIdx.x * 256 + threadIdx.x;
    int e = eidx[t];
    int pos = atomicAdd(&fill[e], 1);
    tlist[pos] = t;
}

// grouped GEMM1: h = relu(X_g @ Wfc[e]^T)^2, stored bf16 grouped
__global__ __launch_bounds__(256) void k_ffn1(
        const float* __restrict__ x, const float* __restrict__ wfc,
        const int* __restrict__ tilee, const int* __restrict__ tlist,
        __hip_bfloat16* __restrict__ hbuf) {
    int rt = blockIdx.y, ct = blockIdx.x;
    int e = tilee[rt];
    if (e < 0) return;
    __shared__ float Xs[16][68];
    __shared__ float Ws[16][68];
    int tid = threadIdx.x;
    int tm = tid & 15, tn = tid >> 4;
    int lr = tid >> 2, lk = (tid & 3) * 4;
    int gtok = tlist[rt * 64 + lr];
    const float* xrow = x + (size_t)(gtok < 0 ? 0 : gtok) * CD;
    const float* wrow = wfc + ((size_t)e * HD + ct * 64 + lr) * CD;
    float acc[4][4] = {};
    for (int k0 = 0; k0 < CD; k0 += 16) {
        float4 xa = *(const float4*)(xrow + k0 + lk);
        float4 wa = *(const float4*)(wrow + k0 + lk);
        __syncthreads();
        Xs[lk + 0][lr] = xa.x; Xs[lk + 1][lr] = xa.y;
        Xs[lk + 2][lr] = xa.z; Xs[lk + 3][lr] = xa.w;
        Ws[lk + 0][lr] = wa.x; Ws[lk + 1][lr] = wa.y;
        Ws[lk + 2][lr] = wa.z; Ws[lk + 3][lr] = wa.w;
        __syncthreads();
        #pragma unroll
        for (int k = 0; k < 16; ++k) {
            float4 av = *(const float4*)(&Xs[k][tm * 4]);
            float4 bv = *(const float4*)(&Ws[k][tn * 4]);
            const float* ap = (const float*)&av;
            const float* bp = (const float*)&bv;
            #pragma unroll
            for (int i = 0; i < 4; ++i)
                #pragma unroll
                for (int j = 0; j < 4; ++j)
                    acc[i][j] = fmaf(ap[i], bp[j], acc[i][j]);
        }
    }
    int colb = ct * 64 + tn * 4;
    #pragma unroll
    for (int i = 0; i < 4; ++i) {
        size_t row = (size_t)rt * 64 + tm * 4 + i;
        __hip_bfloat16* hp = hbuf + row * HD + colb;
        #pragma unroll
        for (int j = 0; j < 4; ++j) {
            float r = fmaxf(acc[i][j], 0.f);
            hp[j] = __float2bfloat16(r * r);
        }
    }
}

// grouped GEMM2: y = H_g @ Wproj[e]^T, scattered back to token order
__global__ __launch_bounds__(256) void k_ffn2(
        const __hip_bfloat16* __restrict__ hbuf, const float* __restrict__ wpr,
        const int* __restrict__ tilee, const int* __restrict__ tlist,
        float* __restrict__ y) {
    int rt = blockIdx.y, ct = blockIdx.x;
    int e = tilee[rt];
    if (e < 0) return;
    __shared__ float Hs[16][68];
    __shared__ float Ws[16][68];
    int tid = threadIdx.x;
    int tm = tid & 15, tn = tid >> 4;
    int lr = tid >> 2, lk = (tid & 3) * 4;
    const unsigned short* hrow = (const unsigned short*)hbuf + (size_t)(rt * 64 + lr) * HD;
    const float* wrow = wpr + ((size_t)e * CD + ct * 64 + lr) * HD;
    float acc[4][4] = {};
    for (int k0 = 0; k0 < HD; k0 += 16) {
        ushort4 ha = *(const ushort4*)(hrow + k0 + lk);
        float4 wa = *(const float4*)(wrow + k0 + lk);
        __syncthreads();
        Hs[lk + 0][lr] = __uint_as_float((unsigned)ha.x << 16);
        Hs[lk + 1][lr] = __uint_as_float((unsigned)ha.y << 16);
        Hs[lk + 2][lr] = __uint_as_float((unsigned)ha.z << 16);
        Hs[lk + 3][lr] = __uint_as_float((unsigned)ha.w << 16);
        Ws[lk + 0][lr] = wa.x; Ws[lk + 1][lr] = wa.y;
        Ws[lk + 2][lr] = wa.z; Ws[lk + 3][lr] = wa.w;
        __syncthreads();
        #pragma unroll
        for (int k = 0; k < 16; ++k) {
            float4 av = *(const float4*)(&Hs[k][tm * 4]);
            float4 bv = *(const float4*)(&Ws[k][tn * 4]);
            const float* ap = (const float*)&av;
            const float* bp = (const float*)&bv;
            #pragma unroll
            for (int i = 0; i < 4; ++i)
                #pragma unroll
                for (int j = 0; j < 4; ++j)
                    acc[i][j] = fmaf(ap[i], bp[j], acc[i][j]);
        }
    }
    int colb = ct * 64 + tn * 4;
    #pragma unroll
    for (int i = 0; i < 4; ++i) {
        int t = tlist[rt * 64 + tm * 4 + i];
        if (t >= 0) {
            float* yp = y + (size_t)t * CD + colb;
            #pragma unroll
            for (int j = 0; j < 4; ++j) yp[j] = acc[i][j];
        }
    }
}

__global__ void k_fin(const int* counts, const float* sprob,
                      const float* zsum, const float* hsum, float* out) {
    float aux = 0.f;
    for (int e = 0; e < NE; ++e) {
        float a = counts[e] / (float)NTOK;
        float ex = sprob[e] / (float)NTOK;
        aux += a * ex;
    }
    out[0] = NE * aux;
    out[1] = (*zsum) / (float)NTOK;
    out[2] = ((*hsum) / (float)NTOK) / logf((float)NE);
    for (int e = 0; e < NE; ++e) out[3 + e] = counts[e] / (float)NTOK;
}

extern "C" void kernel_launch(void* const* d_in, const int* in_sizes, int n_in,
                              void* d_out, int out_size, void* d_ws, size_t ws_size,
                              hipStream_t stream) {
    const float* x   = (const float*)d_in[0];
    const float* wr  = (const float*)d_in[1];
    const float* wfc = (const float*)d_in[2];
    const float* wpr = (const float*)d_in[3];
    float* y = (float*)d_out;

    char* ws = (char*)d_ws;
    int*   eidx   = (int*)(ws + 0);
    int*   counts = (int*)(ws + 32768);
    int*   fill   = (int*)(ws + 32784);
    int*   tilee  = (int*)(ws + 32800);
    float* sprob  = (float*)(ws + 33344);
    float* zsum   = (float*)(ws + 33360);
    float* hsum   = (float*)(ws + 33364);
    int*   tlist  = (int*)(ws + 33792);
    __hip_bfloat16* hbuf = (__hip_bfloat16*)(ws + 131072);

    k_init<<<1, 256, 0, stream>>>(counts, fill, tilee, sprob, zsum, hsum, tlist);
    k_router<<<NTOK / 4, 256, 0, stream>>>(x, wr, eidx, counts, sprob, zsum, hsum);
    k_scan<<<1, 1, 0, stream>>>(counts, fill, tilee);
    k_scatter<<<NTOK / 256, 256, 0, stream>>>(eidx, fill, tlist);
    k_ffn1<<<dim3(HD / 64, MAX_TILES), 256, 0, stream>>>(x, wfc, tilee, tlist, hbuf);
    k_ffn2<<<dim3(CD / 64, MAX_TILES), 256, 0, stream>>>(hbuf, wpr, tilee, tlist, y);
    k_fin<<<1, 1, 0, stream>>>(counts, sprob, zsum, hsum, y + (size_t)NTOK * CD);
}

// Round 2
// 213.654 us; speedup vs baseline: 8.6346x; 8.6346x over previous
//
#include <hip/hip_runtime.h>
#include <hip/hip_bf16.h>
#include <stdint.h>

#define NTOK 8192
#define CD 768
#define HD 3072
#define NE 4
#define MAXT 68            // 128-row tiles: worst case 64+3, +1 slack
#define GCAP (MAXT * 128)  // 8704 grouped (padded) rows

typedef __attribute__((ext_vector_type(8))) __bf16 bf16x8;
typedef __attribute__((ext_vector_type(4))) float f32x4;

__device__ __forceinline__ void gl_lds16(const void* g, void* l) {
    __builtin_amdgcn_global_load_lds(
        (const __attribute__((address_space(1))) uint32_t*)g,
        (__attribute__((address_space(3))) uint32_t*)l, 16, 0, 0);
}

__device__ __forceinline__ unsigned bf16bits(float v) {
    __hip_bfloat16 h = __float2bfloat16(v);
    return (unsigned)*reinterpret_cast<unsigned short*>(&h);
}

__global__ void k_init(int* counts, int* fill, int* tilee,
                       float* sprob, float* zsum, float* hsum, int* tlist) {
    int t = threadIdx.x;
    if (t < NE) { counts[t] = 0; fill[t] = 0; sprob[t] = 0.f; }
    if (t == NE) { *zsum = 0.f; *hsum = 0.f; }
    for (int i = t; i < MAXT; i += 256) tilee[i] = -1;
    for (int i = t; i < GCAP; i += 256) tlist[i] = -1;
}

// fp32 -> bf16 bulk convert, 8 elems/thread
__global__ __launch_bounds__(256) void k_cvt(const float* __restrict__ in,
                                             __hip_bfloat16* __restrict__ out, int n) {
    for (int i = (blockIdx.x * 256 + threadIdx.x) * 8; i < n; i += gridDim.x * 256 * 8) {
        float4 a = *(const float4*)(in + i);
        float4 b = *(const float4*)(in + i + 4);
        union { __hip_bfloat16 h[8]; uint4 u; } pk;
        pk.h[0] = __float2bfloat16(a.x); pk.h[1] = __float2bfloat16(a.y);
        pk.h[2] = __float2bfloat16(a.z); pk.h[3] = __float2bfloat16(a.w);
        pk.h[4] = __float2bfloat16(b.x); pk.h[5] = __float2bfloat16(b.y);
        pk.h[6] = __float2bfloat16(b.z); pk.h[7] = __float2bfloat16(b.w);
        *(uint4*)(out + i) = pk.u;
    }
}

// 256 blocks x 32 tokens: fp32 logits, stats in registers -> LDS -> 10 atomics/block
__global__ __launch_bounds__(256) void k_router(
        const float* __restrict__ x, const float* __restrict__ wr,
        int* __restrict__ eidx, int* __restrict__ counts,
        float* __restrict__ sprob, float* __restrict__ zsum, float* __restrict__ hsum) {
    int lane = threadIdx.x & 63;
    int wave = threadIdx.x >> 6;
    float wrv[NE][12];
    #pragma unroll
    for (int e = 0; e < NE; ++e)
        #pragma unroll
        for (int k = 0; k < 12; ++k) wrv[e][k] = wr[e * CD + k * 64 + lane];
    float sp0 = 0.f, sp1 = 0.f, sp2 = 0.f, sp3 = 0.f, zs = 0.f, hs = 0.f;
    int c0 = 0, c1 = 0, c2 = 0, c3 = 0;
    int t0 = blockIdx.x * 32 + wave * 8;
    for (int it = 0; it < 8; ++it) {
        int t = t0 + it;
        const float* xr = x + (size_t)t * CD;
        float a0 = 0.f, a1 = 0.f, a2 = 0.f, a3 = 0.f;
        #pragma unroll
        for (int k = 0; k < 12; ++k) {
            float xv = xr[k * 64 + lane];
            a0 = fmaf(xv, wrv[0][k], a0);
            a1 = fmaf(xv, wrv[1][k], a1);
            a2 = fmaf(xv, wrv[2][k], a2);
            a3 = fmaf(xv, wrv[3][k], a3);
        }
        #pragma unroll
        for (int off = 32; off; off >>= 1) {
            a0 += __shfl_xor(a0, off); a1 += __shfl_xor(a1, off);
            a2 += __shfl_xor(a2, off); a3 += __shfl_xor(a3, off);
        }
        if (lane == 0) {
            float l[NE] = {a0, a1, a2, a3};
            int best = 0; float m = l[0];
            #pragma unroll
            for (int e = 1; e < NE; ++e) if (l[e] > m) { m = l[e]; best = e; }
            float p[NE], s = 0.f;
            #pragma unroll
            for (int e = 0; e < NE; ++e) { p[e] = expf(l[e] - m); s += p[e]; }
            float inv = 1.f / s, ent = 0.f;
            #pragma unroll
            for (int e = 0; e < NE; ++e) {
                p[e] *= inv;
                ent -= p[e] * logf(p[e] + 1e-9f);
            }
            sp0 += p[0]; sp1 += p[1]; sp2 += p[2]; sp3 += p[3];
            float lse = m + logf(s);
            zs += lse * lse; hs += ent;
            if (best == 0) c0++; else if (best == 1) c1++; else if (best == 2) c2++; else c3++;
            eidx[t] = best;
        }
    }
    __shared__ float red[4][10];
    if (lane == 0) {
        red[wave][0] = sp0; red[wave][1] = sp1; red[wave][2] = sp2; red[wave][3] = sp3;
        red[wave][4] = zs;  red[wave][5] = hs;
        red[wave][6] = (float)c0; red[wave][7] = (float)c1;
        red[wave][8] = (float)c2; red[wave][9] = (float)c3;
    }
    __syncthreads();
    if (threadIdx.x == 0) {
        float a[10];
        #pragma unroll
        for (int j = 0; j < 10; ++j)
            a[j] = red[0][j] + red[1][j] + red[2][j] + red[3][j];
        atomicAdd(&sprob[0], a[0]); atomicAdd(&sprob[1], a[1]);
        atomicAdd(&sprob[2], a[2]); atomicAdd(&sprob[3], a[3]);
        atomicAdd(zsum, a[4]); atomicAdd(hsum, a[5]);
        #pragma unroll
        for (int e = 0; e < NE; ++e) atomicAdd(&counts[e], (int)(a[6 + e] + 0.5f));
    }
}

__global__ void k_scan(const int* counts, int* fill, int* tilee) {
    int base = 0, nt = 0;
    for (int e = 0; e < NE; ++e) {
        fill[e] = base;
        int tiles = (counts[e] + 127) >> 7;
        for (int i = 0; i < tiles; ++i) tilee[nt++] = e;
        base += tiles << 7;
    }
}

// wave-aggregated scatter: <=4 atomics per wave
__global__ __launch_bounds__(256) void k_scatter(const int* __restrict__ eidx,
                                                 int* __restrict__ fill,
                                                 int* __restrict__ tlist) {
    int t = blockIdx.x * 256 + threadIdx.x;
    int e = eidx[t];
    int lane = threadIdx.x & 63;
    unsigned long long below = (1ull << lane) - 1ull;
    int base = 0;
    #pragma unroll
    for (int ee = 0; ee < NE; ++ee) {
        unsigned long long mm = __ballot(e == ee);
        if (e == ee) {
            int leader = __ffsll((unsigned long long)mm) - 1;
            int cnt = __popcll(mm);
            int b = 0;
            if (lane == leader) b = atomicAdd(&fill[ee], cnt);
            b = __shfl(b, leader);
            base = b + __popcll(mm & below);
        }
    }
    tlist[base] = t;
}

// ---- grouped GEMM1: h = relu(Xg @ Wfc[e]^T)^2 -> bf16 hbuf ----
// 128x128 tile, BK=64, 4 waves, mfma 16x16x32 bf16, XOR-swizzled LDS
__global__ __launch_bounds__(256) void k_gemm1(
        const __hip_bfloat16* __restrict__ xb, const __hip_bfloat16* __restrict__ wb,
        const int* __restrict__ tilee, const int* __restrict__ tlist,
        __hip_bfloat16* __restrict__ hbuf) {
    int rt = blockIdx.y, ct = blockIdx.x;
    int e = tilee[rt];
    if (e < 0) return;
    __shared__ __align__(16) __hip_bfloat16 As[128 * 64];
    __shared__ __align__(16) __hip_bfloat16 Bs[128 * 64];
    int tid = threadIdx.x;
    int srow = tid >> 3, schunk = tid & 7;
    const __hip_bfloat16 *asrc[4], *bsrc[4];
    #pragma unroll
    for (int i = 0; i < 4; ++i) {
        int r = i * 32 + srow;
        int gt = tlist[rt * 128 + r];
        if (gt < 0) gt = 0;
        int sc = schunk ^ (r & 7);                 // source-side swizzle (rule #21)
        asrc[i] = xb + (size_t)gt * CD + sc * 8;
        bsrc[i] = wb + ((size_t)e * HD + ct * 128 + r) * CD + sc * 8;
    }
    char* lA = (char*)As;
    char* lB = (char*)Bs;
    int wv = tid >> 6, lane = tid & 63;
    int wr_ = wv >> 1, wc = wv & 1;
    int lrow = lane & 15, lk = lane >> 4;
    f32x4 acc[4][4];
    #pragma unroll
    for (int m = 0; m < 4; ++m)
        #pragma unroll
        for (int n = 0; n < 4; ++n) acc[m][n] = (f32x4){0.f, 0.f, 0.f, 0.f};

    for (int k0 = 0; k0 < CD; k0 += 64) {
        __syncthreads();
        #pragma unroll
        for (int i = 0; i < 4; ++i) {
            gl_lds16(asrc[i] + k0, lA + i * 4096 + tid * 16);
            gl_lds16(bsrc[i] + k0, lB + i * 4096 + tid * 16);
        }
        __syncthreads();
        #pragma unroll
        for (int s = 0; s < 2; ++s) {
            bf16x8 af[4], bq[4];
            #pragma unroll
            for (int m = 0; m < 4; ++m) {
                int r = wr_ * 64 + m * 16 + lrow;
                int c = (lk + s * 4) ^ (r & 7);    // read-side swizzle
                af[m] = *(const bf16x8*)(lA + r * 128 + c * 16);
            }
            #pragma unroll
            for (int n = 0; n < 4; ++n) {
                int r = wc * 64 + n * 16 + lrow;
                int c = (lk + s * 4) ^ (r & 7);
                bq[n] = *(const bf16x8*)(lB + r * 128 + c * 16);
            }
            #pragma unroll
            for (int m = 0; m < 4; ++m)
                #pragma unroll
                for (int n = 0; n < 4; ++n)
                    acc[m][n] = __builtin_amdgcn_mfma_f32_16x16x32_bf16(af[m], bq[n], acc[m][n], 0, 0, 0);
        }
    }
    // epilogue: relu^2 -> bf16, xor-pair pack to 4B stores
    int colb = ct * 128 + wc * 64;
    #pragma unroll
    for (int m = 0; m < 4; ++m) {
        int grow0 = rt * 128 + wr_ * 64 + m * 16 + lk * 4;
        #pragma unroll
        for (int n = 0; n < 4; ++n) {
            #pragma unroll
            for (int q = 0; q < 4; ++q) {
                float v = acc[m][n][q];
                v = fmaxf(v, 0.f); v *= v;
                unsigned b = bf16bits(v);
                unsigned ob = (unsigned)__shfl_xor((int)b, 1);
                if (!(lane & 1)) {
                    size_t row = (size_t)(grow0 + q);
                    *(unsigned*)(hbuf + row * HD + colb + n * 16 + (lrow & 14)) = b | (ob << 16);
                }
            }
        }
    }
}

// ---- grouped GEMM2: y = Hg @ Wproj[e]^T, scatter rows to token order ----
__global__ __launch_bounds__(256) void k_gemm2(
        const __hip_bfloat16* __restrict__ hbuf, const __hip_bfloat16* __restrict__ wb,
        const int* __restrict__ tilee, const int* __restrict__ tlist,
        float* __restrict__ y) {
    int rt = blockIdx.y, ct = blockIdx.x;
    int e = tilee[rt];
    if (e < 0) return;
    __shared__ __align__(16) __hip_bfloat16 As[128 * 64];
    __shared__ __align__(16) __hip_bfloat16 Bs[128 * 64];
    int tid = threadIdx.x;
    int srow = tid >> 3, schunk = tid & 7;
    const __hip_bfloat16 *asrc[4], *bsrc[4];
    #pragma unroll
    for (int i = 0; i < 4; ++i) {
        int r = i * 32 + srow;
        int sc = schunk ^ (r & 7);
        asrc[i] = hbuf + ((size_t)rt * 128 + r) * HD + sc * 8;
        bsrc[i] = wb + ((size_t)e * CD + ct * 128 + r) * HD + sc * 8;
    }
    char* lA = (char*)As;
    char* lB = (char*)Bs;
    int wv = tid >> 6, lane = tid & 63;
    int wr_ = wv >> 1, wc = wv & 1;
    int lrow = lane & 15, lk = lane >> 4;
    f32x4 acc[4][4];
    #pragma unroll
    for (int m = 0; m < 4; ++m)
        #pragma unroll
        for (int n = 0; n < 4; ++n) acc[m][n] = (f32x4){0.f, 0.f, 0.f, 0.f};

    for (int k0 = 0; k0 < HD; k0 += 64) {
        __syncthreads();
        #pragma unroll
        for (int i = 0; i < 4; ++i) {
            gl_lds16(asrc[i] + k0, lA + i * 4096 + tid * 16);
            gl_lds16(bsrc[i] + k0, lB + i * 4096 + tid * 16);
        }
        __syncthreads();
        #pragma unroll
        for (int s = 0; s < 2; ++s) {
            bf16x8 af[4], bq[4];
            #pragma unroll
            for (int m = 0; m < 4; ++m) {
                int r = wr_ * 64 + m * 16 + lrow;
                int c = (lk + s * 4) ^ (r & 7);
                af[m] = *(const bf16x8*)(lA + r * 128 + c * 16);
            }
            #pragma unroll
            for (int n = 0; n < 4; ++n) {
                int r = wc * 64 + n * 16 + lrow;
                int c = (lk + s * 4) ^ (r & 7);
                bq[n] = *(const bf16x8*)(lB + r * 128 + c * 16);
            }
            #pragma unroll
            for (int m = 0; m < 4; ++m)
                #pragma unroll
                for (int n = 0; n < 4; ++n)
                    acc[m][n] = __builtin_amdgcn_mfma_f32_16x16x32_bf16(af[m], bq[n], acc[m][n], 0, 0, 0);
        }
    }
    int colb = ct * 128 + wc * 64;
    #pragma unroll
    for (int m = 0; m < 4; ++m) {
        #pragma unroll
        for (int q = 0; q < 4; ++q) {
            int grow = rt * 128 + wr_ * 64 + m * 16 + lk * 4 + q;
            int t = tlist[grow];
            if (t >= 0) {
                float* yp = y + (size_t)t * CD + colb + lrow;
                #pragma unroll
                for (int n = 0; n < 4; ++n) yp[n * 16] = acc[m][n][q];
            }
        }
    }
}

__global__ void k_fin(const int* counts, const float* sprob,
                      const float* zsum, const float* hsum, float* out) {
    float aux = 0.f;
    for (int e = 0; e < NE; ++e) {
        float a = counts[e] / (float)NTOK;
        float ex = sprob[e] / (float)NTOK;
        aux += a * ex;
    }
    out[0] = NE * aux;
    out[1] = (*zsum) / (float)NTOK;
    out[2] = ((*hsum) / (float)NTOK) / logf((float)NE);
    for (int e = 0; e < NE; ++e) out[3 + e] = counts[e] / (float)NTOK;
}

extern "C" void kernel_launch(void* const* d_in, const int* in_sizes, int n_in,
                              void* d_out, int out_size, void* d_ws, size_t ws_size,
                              hipStream_t stream) {
    const float* x   = (const float*)d_in[0];
    const float* wr  = (const float*)d_in[1];
    const float* wfc = (const float*)d_in[2];
    const float* wpr = (const float*)d_in[3];
    float* y = (float*)d_out;

    char* ws = (char*)d_ws;
    int*   eidx   = (int*)ws;                    // 8192 ints
    int*   counts = (int*)(ws + 32768);
    int*   fill   = (int*)(ws + 32800);
    int*   tilee  = (int*)(ws + 32832);          // 68 ints
    float* sprob  = (float*)(ws + 33152);
    float* zsum   = (float*)(ws + 33168);
    float* hsum   = (float*)(ws + 33172);
    int*   tlist  = (int*)(ws + 33280);          // 8704 ints
    __hip_bfloat16* xb   = (__hip_bfloat16*)(ws + 68352);
    __hip_bfloat16* wfcb = (__hip_bfloat16*)(ws + 68352 + 12582912);
    __hip_bfloat16* wprb = (__hip_bfloat16*)(ws + 68352 + 12582912 + 18874368);
    __hip_bfloat16* hbuf = (__hip_bfloat16*)(ws + 68352 + 12582912 + 2 * 18874368);
    // total ws use: ~103.9 MB

    k_init<<<1, 256, 0, stream>>>(counts, fill, tilee, sprob, zsum, hsum, tlist);
    k_cvt<<<3072, 256, 0, stream>>>(x, xb, NTOK * CD);
    k_cvt<<<4608, 256, 0, stream>>>(wfc, wfcb, NE * HD * CD);
    k_cvt<<<4608, 256, 0, stream>>>(wpr, wprb, NE * CD * HD);
    k_router<<<256, 256, 0, stream>>>(x, wr, eidx, counts, sprob, zsum, hsum);
    k_scan<<<1, 1, 0, stream>>>(counts, fill, tilee);
    k_scatter<<<NTOK / 256, 256, 0, stream>>>(eidx, fill, tlist);
    k_gemm1<<<dim3(HD / 128, MAXT), 256, 0, stream>>>(xb, wfcb, tilee, tlist, hbuf);
    k_gemm2<<<dim3(CD / 128, MAXT), 256, 0, stream>>>(hbuf, wprb, tilee, tlist, y);
    k_fin<<<1, 1, 0, stream>>>(counts, sprob, zsum, hsum, y + (size_t)NTOK * CD);
}

// Round 3
// 187.369 us; speedup vs baseline: 9.8459x; 1.1403x over previous
//
#include <hip/hip_runtime.h>
#include <hip/hip_bf16.h>
#include <stdint.h>

#define NTOK 8192
#define CD 768
#define HD 3072
#define NE 4
#define MAXT 36            // 256-row tiles: worst case 33+2, +slack
#define GCAP (MAXT * 256)  // 9216 grouped (padded) rows

typedef __attribute__((ext_vector_type(8))) __bf16 bf16x8;
typedef __attribute__((ext_vector_type(4))) float f32x4;

__device__ __forceinline__ void gl_lds16(const void* g, void* l) {
    __builtin_amdgcn_global_load_lds(
        (const __attribute__((address_space(1))) uint32_t*)g,
        (__attribute__((address_space(3))) uint32_t*)l, 16, 0, 0);
}

__device__ __forceinline__ unsigned bf16bits(float v) {
    __hip_bfloat16 h = __float2bfloat16(v);
    return (unsigned)*reinterpret_cast<unsigned short*>(&h);
}

// -------- weight convert (both) + metadata init --------
__global__ __launch_bounds__(256) void k_cvtw(
        const float* __restrict__ wfc, const float* __restrict__ wpr,
        __hip_bfloat16* __restrict__ wfcb, __hip_bfloat16* __restrict__ wprb,
        int* counts, int* fill, int* tilee,
        float* sprob, float* zsum, float* hsum, int* tlist) {
    if (blockIdx.x == 0) {
        int t = threadIdx.x;
        if (t < NE) { counts[t] = 0; fill[t] = 0; sprob[t] = 0.f; }
        if (t == NE) { *zsum = 0.f; *hsum = 0.f; }
        for (int i = t; i < MAXT; i += 256) tilee[i] = -1;
        for (int i = t; i < GCAP; i += 256) tlist[i] = -1;
    }
    const int NW = NE * HD * CD;
    const int stride = gridDim.x * 256 * 8;
    for (int i = (blockIdx.x * 256 + threadIdx.x) * 8; i < NW; i += stride) {
        float4 a = *(const float4*)(wfc + i);
        float4 b = *(const float4*)(wfc + i + 4);
        union { __hip_bfloat16 h[8]; uint4 u; } pk;
        pk.h[0] = __float2bfloat16(a.x); pk.h[1] = __float2bfloat16(a.y);
        pk.h[2] = __float2bfloat16(a.z); pk.h[3] = __float2bfloat16(a.w);
        pk.h[4] = __float2bfloat16(b.x); pk.h[5] = __float2bfloat16(b.y);
        pk.h[6] = __float2bfloat16(b.z); pk.h[7] = __float2bfloat16(b.w);
        *(uint4*)(wfcb + i) = pk.u;
    }
    for (int i = (blockIdx.x * 256 + threadIdx.x) * 8; i < NW; i += stride) {
        float4 a = *(const float4*)(wpr + i);
        float4 b = *(const float4*)(wpr + i + 4);
        union { __hip_bfloat16 h[8]; uint4 u; } pk;
        pk.h[0] = __float2bfloat16(a.x); pk.h[1] = __float2bfloat16(a.y);
        pk.h[2] = __float2bfloat16(a.z); pk.h[3] = __float2bfloat16(a.w);
        pk.h[4] = __float2bfloat16(b.x); pk.h[5] = __float2bfloat16(b.y);
        pk.h[6] = __float2bfloat16(b.z); pk.h[7] = __float2bfloat16(b.w);
        *(uint4*)(wprb + i) = pk.u;
    }
}

// -------- router (fp32 logits, block-reduced stats) + x->bf16 convert --------
__global__ __launch_bounds__(256) void k_router(
        const float* __restrict__ x, const float* __restrict__ wr,
        __hip_bfloat16* __restrict__ xb, int* __restrict__ eidx, int* __restrict__ counts,
        float* __restrict__ sprob, float* __restrict__ zsum, float* __restrict__ hsum) {
    int lane = threadIdx.x & 63;
    int wave = threadIdx.x >> 6;
    float4 wv[NE][3];
    #pragma unroll
    for (int e = 0; e < NE; ++e)
        #pragma unroll
        for (int j = 0; j < 3; ++j)
            wv[e][j] = *(const float4*)(wr + e * CD + j * 256 + lane * 4);
    float sp0 = 0.f, sp1 = 0.f, sp2 = 0.f, sp3 = 0.f, zs = 0.f, hs = 0.f;
    int c0 = 0, c1 = 0, c2 = 0, c3 = 0;
    int t0 = blockIdx.x * 32 + wave * 8;
    for (int it = 0; it < 8; ++it) {
        int t = t0 + it;
        const float* xr = x + (size_t)t * CD;
        float a0 = 0.f, a1 = 0.f, a2 = 0.f, a3 = 0.f;
        #pragma unroll
        for (int j = 0; j < 3; ++j) {
            float4 xv = *(const float4*)(xr + j * 256 + lane * 4);
            a0 += xv.x * wv[0][j].x + xv.y * wv[0][j].y + xv.z * wv[0][j].z + xv.w * wv[0][j].w;
            a1 += xv.x * wv[1][j].x + xv.y * wv[1][j].y + xv.z * wv[1][j].z + xv.w * wv[1][j].w;
            a2 += xv.x * wv[2][j].x + xv.y * wv[2][j].y + xv.z * wv[2][j].z + xv.w * wv[2][j].w;
            a3 += xv.x * wv[3][j].x + xv.y * wv[3][j].y + xv.z * wv[3][j].z + xv.w * wv[3][j].w;
        }
        #pragma unroll
        for (int off = 32; off; off >>= 1) {
            a0 += __shfl_xor(a0, off); a1 += __shfl_xor(a1, off);
            a2 += __shfl_xor(a2, off); a3 += __shfl_xor(a3, off);
        }
        if (lane == 0) {
            float l[NE] = {a0, a1, a2, a3};
            int best = 0; float m = l[0];
            #pragma unroll
            for (int e = 1; e < NE; ++e) if (l[e] > m) { m = l[e]; best = e; }
            float p[NE], s = 0.f;
            #pragma unroll
            for (int e = 0; e < NE; ++e) { p[e] = expf(l[e] - m); s += p[e]; }
            float inv = 1.f / s, ent = 0.f;
            #pragma unroll
            for (int e = 0; e < NE; ++e) {
                p[e] *= inv;
                ent -= p[e] * logf(p[e] + 1e-9f);
            }
            sp0 += p[0]; sp1 += p[1]; sp2 += p[2]; sp3 += p[3];
            float lse = m + logf(s);
            zs += lse * lse; hs += ent;
            if (best == 0) c0++; else if (best == 1) c1++; else if (best == 2) c2++; else c3++;
            eidx[t] = best;
        }
    }
    __shared__ float red[4][10];
    if (lane == 0) {
        red[wave][0] = sp0; red[wave][1] = sp1; red[wave][2] = sp2; red[wave][3] = sp3;
        red[wave][4] = zs;  red[wave][5] = hs;
        red[wave][6] = (float)c0; red[wave][7] = (float)c1;
        red[wave][8] = (float)c2; red[wave][9] = (float)c3;
    }
    __syncthreads();
    if (threadIdx.x == 0) {
        float a[10];
        #pragma unroll
        for (int j = 0; j < 10; ++j)
            a[j] = red[0][j] + red[1][j] + red[2][j] + red[3][j];
        atomicAdd(&sprob[0], a[0]); atomicAdd(&sprob[1], a[1]);
        atomicAdd(&sprob[2], a[2]); atomicAdd(&sprob[3], a[3]);
        atomicAdd(zsum, a[4]); atomicAdd(hsum, a[5]);
        #pragma unroll
        for (int e = 0; e < NE; ++e) atomicAdd(&counts[e], (int)(a[6 + e] + 0.5f));
    }
    // fused x -> bf16 (this block's 32 rows)
    const float* xsrc = x + (size_t)blockIdx.x * 32 * CD;
    __hip_bfloat16* xdst = xb + (size_t)blockIdx.x * 32 * CD;
    #pragma unroll
    for (int c = 0; c < 12; ++c) {
        int i = (c * 256 + threadIdx.x) * 8;
        float4 a = *(const float4*)(xsrc + i);
        float4 b = *(const float4*)(xsrc + i + 4);
        union { __hip_bfloat16 h[8]; uint4 u; } pk;
        pk.h[0] = __float2bfloat16(a.x); pk.h[1] = __float2bfloat16(a.y);
        pk.h[2] = __float2bfloat16(a.z); pk.h[3] = __float2bfloat16(a.w);
        pk.h[4] = __float2bfloat16(b.x); pk.h[5] = __float2bfloat16(b.y);
        pk.h[6] = __float2bfloat16(b.z); pk.h[7] = __float2bfloat16(b.w);
        *(uint4*)(xdst + i) = pk.u;
    }
}

__global__ void k_scan(const int* counts, int* fill, int* tilee) {
    int base = 0, nt = 0;
    for (int e = 0; e < NE; ++e) {
        fill[e] = base;
        int tiles = (counts[e] + 255) >> 8;
        for (int i = 0; i < tiles; ++i) tilee[nt++] = e;
        base += tiles << 8;
    }
}

// wave-aggregated scatter
__global__ __launch_bounds__(256) void k_scatter(const int* __restrict__ eidx,
                                                 int* __restrict__ fill,
                                                 int* __restrict__ tlist) {
    int t = blockIdx.x * 256 + threadIdx.x;
    int e = eidx[t];
    int lane = threadIdx.x & 63;
    unsigned long long below = (1ull << lane) - 1ull;
    int base = 0;
    #pragma unroll
    for (int ee = 0; ee < NE; ++ee) {
        unsigned long long mm = __ballot(e == ee);
        if (e == ee) {
            int leader = __ffsll((unsigned long long)mm) - 1;
            int cnt = __popcll(mm);
            int b = 0;
            if (lane == leader) b = atomicAdd(&fill[ee], cnt);
            b = __shfl(b, leader);
            base = b + __popcll(mm & below);
        }
    }
    tlist[base] = t;
}

// -------- grouped GEMM, 4-phase/K-tile counted-vmcnt schedule --------
// MODE 1: hbuf = relu(Xg @ Wfc^T)^2 (bf16); MODE 2: y = Hg @ Wproj^T (fp32 scatter)
template<int MODE, int BN, int WAVES_M, int WAVES_N, int NT>
__global__ __launch_bounds__(512, 2) void k_gemm(
        const __hip_bfloat16* __restrict__ A, const __hip_bfloat16* __restrict__ Bw,
        const int* __restrict__ tilee, const int* __restrict__ tlist,
        void* __restrict__ outp) {
    constexpr int KDIM  = (MODE == 1) ? CD : HD;
    constexpr int NBROW = (MODE == 1) ? HD : CD;
    constexpr int WM = 256 / WAVES_M, WN = BN / WAVES_N;
    constexpr int MFR = WM / 16, MH = MFR / 2;          // m-frags, per-phase half
    constexpr int APL = 16384;                          // A plane: 256r x 32k bf16
    constexpr int BPL = BN * 64;                        // B plane: BN r x 32k bf16
    constexpr int BBASE = 4 * APL;
    constexpr int BLD = BPL / 8192;                     // B loads per thread per plane
    __shared__ __align__(16) char lds[BBASE + 4 * BPL];

    const int rt = blockIdx.y, ct = blockIdx.x;
    const int e = tilee[rt];
    if (e < 0) return;
    const int tid = threadIdx.x;
    const int scol = ((tid & 3) ^ ((tid >> 3) & 3)) << 3;   // pre-swizzled source col

    const __hip_bfloat16 *aptr0, *aptr1;
    if constexpr (MODE == 1) {
        int g0 = tlist[rt * 256 + (tid >> 2)];       if (g0 < 0) g0 = 0;
        int g1 = tlist[rt * 256 + 128 + (tid >> 2)]; if (g1 < 0) g1 = 0;
        aptr0 = A + (size_t)g0 * KDIM + scol;
        aptr1 = A + (size_t)g1 * KDIM + scol;
    } else {
        aptr0 = A + ((size_t)rt * 256 + (tid >> 2)) * KDIM + scol;
        aptr1 = aptr0 + (size_t)128 * KDIM;
    }
    const __hip_bfloat16* bptr0 = Bw + ((size_t)e * NBROW + ct * BN + (tid >> 2)) * KDIM + scol;
    const __hip_bfloat16* bptr1 = bptr0 + (size_t)128 * KDIM;

    auto stageA = [&](int slot, int kh, int kt2) {
        char* dst = lds + slot * 2 * APL + kh * APL + tid * 16;
        size_t ko = (size_t)kt2 * 64 + kh * 32;
        gl_lds16(aptr0 + ko, dst);
        gl_lds16(aptr1 + ko, dst + 8192);
    };
    auto stageB = [&](int slot, int kh, int kt2) {
        char* dst = lds + BBASE + slot * 2 * BPL + kh * BPL + tid * 16;
        size_t ko = (size_t)kt2 * 64 + kh * 32;
        gl_lds16(bptr0 + ko, dst);
        if constexpr (BLD == 2) gl_lds16(bptr1 + ko, dst + 8192);
    };

    const int wv = tid >> 6, lane = tid & 63;
    const int wm = wv / WAVES_N, wn = wv % WAVES_N;
    const int lr = lane & 15, lq = lane >> 4;

    auto lda = [&](int slot, int kh, int f) -> bf16x8 {
        int r = wm * WM + f * 16 + lr;
        int off = slot * 2 * APL + kh * APL + r * 64 + ((lq ^ ((r >> 1) & 3)) << 4);
        return *(const bf16x8*)(lds + off);
    };
    auto ldb = [&](int slot, int kh, int g) -> bf16x8 {
        int r = wn * WN + g * 16 + lr;
        int off = BBASE + slot * 2 * BPL + kh * BPL + r * 64 + ((lq ^ ((r >> 1) & 3)) << 4);
        return *(const bf16x8*)(lds + off);
    };

    f32x4 acc[MFR][4];
    #pragma unroll
    for (int f = 0; f < MFR; ++f)
        #pragma unroll
        for (int g = 0; g < 4; ++g) acc[f][g] = (f32x4){0.f, 0.f, 0.f, 0.f};

    // prologue: stage kt=0 (slot 0) in steady issue order
    stageA(0, 0, 0); stageB(0, 0, 0); stageA(0, 1, 0); stageB(0, 1, 0);

    #define VMWAIT() do { \
        if constexpr (BLD == 2) asm volatile("s_waitcnt vmcnt(6)" ::: "memory"); \
        else                    asm volatile("s_waitcnt vmcnt(5)" ::: "memory"); } while (0)
    #define VMWAIT0() asm volatile("s_waitcnt vmcnt(0)" ::: "memory")
    #define BAR() do { __builtin_amdgcn_s_barrier(); __builtin_amdgcn_sched_barrier(0); } while (0)

    #pragma unroll 2
    for (int kt = 0; kt < NT; ++kt) {
        const int s = kt & 1, ns = s ^ 1;
        const bool pf = (kt + 1 < NT);
        bf16x8 bfr[4], afr[MH];
        // ---- phase 0: (mh0, kh0) ----
        if (pf) { stageA(ns, 0, kt + 1); VMWAIT(); } else VMWAIT0();
        BAR();
        #pragma unroll
        for (int g = 0; g < 4; ++g) bfr[g] = ldb(s, 0, g);
        #pragma unroll
        for (int i = 0; i < MH; ++i) afr[i] = lda(s, 0, i);
        __builtin_amdgcn_s_setprio(1);
        #pragma unroll
        for (int i = 0; i < MH; ++i)
            #pragma unroll
            for (int g = 0; g < 4; ++g)
                acc[i][g] = __builtin_amdgcn_mfma_f32_16x16x32_bf16(afr[i], bfr[g], acc[i][g], 0, 0, 0);
        __builtin_amdgcn_s_setprio(0);
        // ---- phase 1: (mh1, kh0) ----
        if (pf) stageB(ns, 0, kt + 1);
        BAR();
        #pragma unroll
        for (int i = 0; i < MH; ++i) afr[i] = lda(s, 0, MH + i);
        __builtin_amdgcn_s_setprio(1);
        #pragma unroll
        for (int i = 0; i < MH; ++i)
            #pragma unroll
            for (int g = 0; g < 4; ++g)
                acc[MH + i][g] = __builtin_amdgcn_mfma_f32_16x16x32_bf16(afr[i], bfr[g], acc[MH + i][g], 0, 0, 0);
        __builtin_amdgcn_s_setprio(0);
        // ---- phase 2: (mh1, kh1) ----
        if (pf) { stageA(ns, 1, kt + 1); VMWAIT(); } else VMWAIT0();
        BAR();
        #pragma unroll
        for (int g = 0; g < 4; ++g) bfr[g] = ldb(s, 1, g);
        #pragma unroll
        for (int i = 0; i < MH; ++i) afr[i] = lda(s, 1, MH + i);
        __builtin_amdgcn_s_setprio(1);
        #pragma unroll
        for (int i = 0; i < MH; ++i)
            #pragma unroll
            for (int g = 0; g < 4; ++g)
                acc[MH + i][g] = __builtin_amdgcn_mfma_f32_16x16x32_bf16(afr[i], bfr[g], acc[MH + i][g], 0, 0, 0);
        __builtin_amdgcn_s_setprio(0);
        // ---- phase 3: (mh0, kh1) ----
        if (pf) stageB(ns, 1, kt + 1);
        BAR();
        #pragma unroll
        for (int i = 0; i < MH; ++i) afr[i] = lda(s, 1, i);
        __builtin_amdgcn_s_setprio(1);
        #pragma unroll
        for (int i = 0; i < MH; ++i)
            #pragma unroll
            for (int g = 0; g < 4; ++g)
                acc[i][g] = __builtin_amdgcn_mfma_f32_16x16x32_bf16(afr[i], bfr[g], acc[i][g], 0, 0, 0);
        __builtin_amdgcn_s_setprio(0);
    }

    if constexpr (MODE == 1) {
        __hip_bfloat16* hbuf = (__hip_bfloat16*)outp;
        int colb = ct * BN + wn * WN;
        #pragma unroll
        for (int f = 0; f < MFR; ++f) {
            int row0 = rt * 256 + wm * WM + f * 16 + lq * 4;
            #pragma unroll
            for (int g = 0; g < 4; ++g) {
                #pragma unroll
                for (int q = 0; q < 4; ++q) {
                    float v = fmaxf(acc[f][g][q], 0.f);
                    v *= v;
                    unsigned b = bf16bits(v);
                    unsigned ob = (unsigned)__shfl_xor((int)b, 1);
                    if (!(lane & 1))
                        *(unsigned*)(hbuf + (size_t)(row0 + q) * HD + colb + g * 16 + (lr & 14)) = b | (ob << 16);
                }
            }
        }
    } else {
        float* y = (float*)outp;
        #pragma unroll
        for (int f = 0; f < MFR; ++f) {
            #pragma unroll
            for (int q = 0; q < 4; ++q) {
                int grow = rt * 256 + wm * WM + f * 16 + lq * 4 + q;
                int t = tlist[grow];
                if (t >= 0) {
                    float* yp = y + (size_t)t * CD + ct * BN + wn * WN + lr;
                    #pragma unroll
                    for (int g = 0; g < 4; ++g) yp[g * 16] = acc[f][g][q];
                }
            }
        }
    }
    #undef VMWAIT
    #undef VMWAIT0
    #undef BAR
}

__global__ void k_fin(const int* counts, const float* sprob,
                      const float* zsum, const float* hsum, float* out) {
    float aux = 0.f;
    for (int e = 0; e < NE; ++e) {
        float a = counts[e] / (float)NTOK;
        float ex = sprob[e] / (float)NTOK;
        aux += a * ex;
    }
    out[0] = NE * aux;
    out[1] = (*zsum) / (float)NTOK;
    out[2] = ((*hsum) / (float)NTOK) / logf((float)NE);
    for (int e = 0; e < NE; ++e) out[3 + e] = counts[e] / (float)NTOK;
}

extern "C" void kernel_launch(void* const* d_in, const int* in_sizes, int n_in,
                              void* d_out, int out_size, void* d_ws, size_t ws_size,
                              hipStream_t stream) {
    const float* x   = (const float*)d_in[0];
    const float* wr  = (const float*)d_in[1];
    const float* wfc = (const float*)d_in[2];
    const float* wpr = (const float*)d_in[3];
    float* y = (float*)d_out;

    char* ws = (char*)d_ws;
    int*   eidx   = (int*)ws;                          // 8192 ints
    int*   counts = (int*)(ws + 32768);
    int*   fill   = (int*)(ws + 32800);
    int*   tilee  = (int*)(ws + 32832);                // 36 ints
    float* sprob  = (float*)(ws + 33024);
    float* zsum   = (float*)(ws + 33040);
    float* hsum   = (float*)(ws + 33044);
    int*   tlist  = (int*)(ws + 33280);                // 9216 ints -> ends 70144
    __hip_bfloat16* xb   = (__hip_bfloat16*)(ws + 70656);                 // 12.6 MB
    __hip_bfloat16* wfcb = (__hip_bfloat16*)(ws + 70656 + 12582912);      // 18.9 MB
    __hip_bfloat16* wprb = (__hip_bfloat16*)(ws + 70656 + 12582912 + 18874368);
    __hip_bfloat16* hbuf = (__hip_bfloat16*)(ws + 70656 + 12582912 + 2 * 18874368);
    // total ws use ~102.1 MB

    k_cvtw<<<2048, 256, 0, stream>>>(wfc, wpr, wfcb, wprb,
                                     counts, fill, tilee, sprob, zsum, hsum, tlist);
    k_router<<<256, 256, 0, stream>>>(x, wr, xb, eidx, counts, sprob, zsum, hsum);
    k_scan<<<1, 1, 0, stream>>>(counts, fill, tilee);
    k_scatter<<<NTOK / 256, 256, 0, stream>>>(eidx, fill, tlist);
    k_gemm<1, 256, 2, 4, 12><<<dim3(HD / 256, MAXT), 512, 0, stream>>>(xb, wfcb, tilee, tlist, hbuf);
    k_gemm<2, 128, 4, 2, 48><<<dim3(CD / 128, MAXT), 512, 0, stream>>>(hbuf, wprb, tilee, tlist, y);
    k_fin<<<1, 1, 0, stream>>>(counts, sprob, zsum, hsum, y + (size_t)NTOK * CD);
}